// Round 18
// baseline (281.489 us; speedup 1.0000x reference)
//
#include <hip/hip_runtime.h>

#define IN_DIM 128
#define F1 256      // HEADS*HID = 4*64
#define HID 64
#define OUT_DIM 32
#define NEG 0.2f
#define PADK 136    // LDS row pitch in bf16 elems (128 + 8): frag reads 2-way alias = free

typedef __attribute__((ext_vector_type(8))) short short8;
typedef __attribute__((ext_vector_type(4))) float v4f;
typedef __attribute__((ext_vector_type(2))) float v2f;

// ---- bf16 helpers ----
__device__ __forceinline__ float b2fl(unsigned u) {
  union { unsigned i; float f; } c; c.i = u << 16; return c.f;
}
__device__ __forceinline__ float b2fh(unsigned u) {
  union { unsigned i; float f; } c; c.i = u & 0xffff0000u; return c.f;
}
__device__ __forceinline__ unsigned short f2b(float f) {
  union { float f; unsigned i; } c; c.f = f;
  unsigned r = c.i + 0x7fffu + ((c.i >> 16) & 1u);   // RNE
  return (unsigned short)(r >> 16);
}

// ---- merged prep + hist ----
__global__ __launch_bounds__(256) void k_prep_hist(const float* __restrict__ W1,
    unsigned short* __restrict__ W1t, const float* __restrict__ W2,
    unsigned short* __restrict__ W2t, const int* __restrict__ adj,
    int* __restrict__ cnt, int* __restrict__ rank, int E_, int n) {
  const int b = blockIdx.x;
  if (b < 128) {            // W1t[n][k] = W1[k][n], 32768 elems
    int idx = b * 256 + threadIdx.x;
    int nn = idx >> 7, k = idx & 127;
    W1t[idx] = f2b(W1[(size_t)k * F1 + nn]);
    return;
  }
  if (b < 160) {            // W2t[n][k] = W2[k][n], 8192 elems
    int idx = (b - 128) * 256 + threadIdx.x;
    int nn = idx >> 8, k = idx & 255;
    W2t[idx] = f2b(W2[(size_t)k * OUT_DIM + nn]);
    return;
  }
  int e = (b - 160) * 256 + threadIdx.x;
  int ET = E_ + n;
  if (e >= ET) return;
  int d = (e < E_) ? adj[E_ + e] : (e - E_);
  rank[e] = atomicAdd(&cnt[d], 1);
}

// ------- GEMM1 via MFMA: h1f8[N,256](fp8 e4m3) = bf16(x)[N,128] @ W1[128,256] -------
// x tile staged ONCE per 64-row block; loop over the 4 heads reusing ws.
__global__ __launch_bounds__(256) void k_gemm1(const float* __restrict__ x,
    const unsigned short* __restrict__ W1t,
    const float* __restrict__ a1s_w, const float* __restrict__ a1d_w,
    unsigned char* __restrict__ h1f8, float* __restrict__ as1,
    float* __restrict__ ad1, int n) {
  __shared__ unsigned short xs[64 * PADK];   // 17.4 KB
  __shared__ unsigned short ws[64 * PADK];   // 17.4 KB (reused per head)
  const int tid = threadIdx.x;
  const int rb = blockIdx.x * 64;

#pragma unroll
  for (int i = 0; i < 8; ++i) {
    int idx = tid + i * 256;
    int row = idx >> 5, c4 = idx & 31;
    float4 v = make_float4(0.f, 0.f, 0.f, 0.f);
    if (rb + row < n) v = *(const float4*)&x[(size_t)(rb + row) * IN_DIM + c4 * 4];
    ushort4 b; b.x = f2b(v.x); b.y = f2b(v.y); b.z = f2b(v.z); b.w = f2b(v.w);
    *(ushort4*)&xs[row * PADK + c4 * 4] = b;
  }

  const int wv = tid >> 6;
  const int lane = tid & 63;
  const int l15 = lane & 15, quad = lane >> 4;

  for (int head = 0; head < 4; ++head) {
    const int cb = head * 64;
#pragma unroll
    for (int i = 0; i < 4; ++i) {
      int idx = tid + i * 256;
      int row = idx >> 4, c = idx & 15;
      *(uint4*)&ws[row * PADK + c * 8] =
          *(const uint4*)&W1t[(size_t)(cb + row) * IN_DIM + c * 8];
    }
    __syncthreads();

    v4f acc0 = {0.f, 0.f, 0.f, 0.f}, acc1 = acc0, acc2 = acc0, acc3 = acc0;
#pragma unroll
    for (int kt = 0; kt < 4; ++kt) {
      const int ko = kt * 32 + quad * 8;
      short8 af = *(const short8*)&xs[(wv * 16 + l15) * PADK + ko];
      short8 b0 = *(const short8*)&ws[(l15) * PADK + ko];
      short8 b1 = *(const short8*)&ws[(16 + l15) * PADK + ko];
      short8 b2 = *(const short8*)&ws[(32 + l15) * PADK + ko];
      short8 b3 = *(const short8*)&ws[(48 + l15) * PADK + ko];
      acc0 = __builtin_amdgcn_mfma_f32_16x16x32_bf16(af, b0, acc0, 0, 0, 0);
      acc1 = __builtin_amdgcn_mfma_f32_16x16x32_bf16(af, b1, acc1, 0, 0, 0);
      acc2 = __builtin_amdgcn_mfma_f32_16x16x32_bf16(af, b2, acc2, 0, 0, 0);
      acc3 = __builtin_amdgcn_mfma_f32_16x16x32_bf16(af, b3, acc3, 0, 0, 0);
    }

    const float s0 = a1s_w[cb + l15],      s1 = a1s_w[cb + 16 + l15];
    const float s2 = a1s_w[cb + 32 + l15], s3 = a1s_w[cb + 48 + l15];
    const float d0 = a1d_w[cb + l15],      d1 = a1d_w[cb + 16 + l15];
    const float d2 = a1d_w[cb + 32 + l15], d3 = a1d_w[cb + 48 + l15];
#pragma unroll
    for (int r = 0; r < 4; ++r) {
      const int row = rb + wv * 16 + quad * 4 + r;
      const bool ok = row < n;
      if (ok) {
        size_t base = (size_t)row * F1 + cb;
        int pA = __builtin_amdgcn_cvt_pk_fp8_f32(acc0[r], acc1[r], 0, false);
        int pB = __builtin_amdgcn_cvt_pk_fp8_f32(acc2[r], acc3[r], 0, false);
        h1f8[base + l15]      = (unsigned char)(pA & 0xff);
        h1f8[base + 16 + l15] = (unsigned char)((pA >> 8) & 0xff);
        h1f8[base + 32 + l15] = (unsigned char)(pB & 0xff);
        h1f8[base + 48 + l15] = (unsigned char)((pB >> 8) & 0xff);
      }
      float ds = acc0[r] * s0 + acc1[r] * s1 + acc2[r] * s2 + acc3[r] * s3;
      float dd = acc0[r] * d0 + acc1[r] * d1 + acc2[r] * d2 + acc3[r] * d3;
#pragma unroll
      for (int m = 1; m <= 8; m <<= 1) {
        ds += __shfl_xor(ds, m, 64);
        dd += __shfl_xor(dd, m, 64);
      }
      if (ok && l15 == 0) {
        as1[(size_t)row * 4 + head] = ds;
        ad1[(size_t)row * 4 + head] = dd;
      }
    }
    __syncthreads();   // ws reuse barrier
  }
}

// scan phase A: per-1024-chunk local exclusive scan; block 0 zeroes gsum/gcnt
__global__ __launch_bounds__(256) void k_scan_local(const int* __restrict__ cnt,
    int* __restrict__ offs, int* __restrict__ bsum,
    float* __restrict__ gsum, float* __restrict__ gcnt, int n) {
  __shared__ int wsums[4];
  const int tid = threadIdx.x;
  if (blockIdx.x == 0 && tid < 64) { gsum[tid] = 0.f; gcnt[tid] = 0.f; }
  const int lane = tid & 63, w = tid >> 6;
  const int base = blockIdx.x * 1024;
  const int i0 = base + tid * 4;
  int v[4];
#pragma unroll
  for (int k = 0; k < 4; ++k) { int i = i0 + k; v[k] = (i < n) ? cnt[i] : 0; }
  int tsum = v[0] + v[1] + v[2] + v[3];
  int incl = tsum;
#pragma unroll
  for (int d = 1; d < 64; d <<= 1) {
    int t = __shfl_up(incl, (unsigned)d, 64);
    if (lane >= d) incl += t;
  }
  if (lane == 63) wsums[w] = incl;
  __syncthreads();
  int pre = 0;
  for (int k = 0; k < w; ++k) pre += wsums[k];
  int run = pre + incl - tsum;
#pragma unroll
  for (int k = 0; k < 4; ++k) { int i = i0 + k; if (i < n) offs[i] = run; run += v[k]; }
  if (tid == 255) bsum[blockIdx.x] = pre + incl;
}

// scan phase B (merged bsum-scan + add); NB<=64 (N=50000 -> 49)
__global__ __launch_bounds__(256) void k_scan_add(int* __restrict__ offs,
    const int* __restrict__ bsum, int n, int nb) {
  __shared__ int pre_s, tot_s;
  const int tid = threadIdx.x;
  if (tid < 64) {
    int v = (tid < nb) ? bsum[tid] : 0;
    int incl = v;
#pragma unroll
    for (int d = 1; d < 64; d <<= 1) {
      int t = __shfl_up(incl, (unsigned)d, 64);
      if (tid >= d) incl += t;
    }
    int excl = incl - v;
    int pre = __shfl(excl, blockIdx.x >> 2, 64);
    int tot = __shfl(incl, nb - 1, 64);
    if (tid == 0) { pre_s = pre; tot_s = tot; }
  }
  __syncthreads();
  int i = blockIdx.x * 256 + tid;
  if (i < n) offs[i] += pre_s;
  if (blockIdx.x == 0 && tid == 0) offs[n] = tot_s;
}

// -------- build: INVERTED scatter (R18) --------
// R9-R15 lesson: random 16B HBM *writes* are the most expensive op class here
// (line thrash, ~60 MB WRITE for 13.6 MB logical). Inverted: edge records go
// to wtab[e] in EDGE order (fully coalesced); only a 4B perm index is scattered
// (random writes span 3.4 MB -> L2-resident, k_hist-cheap). agg kernels pay a
// cache-resident random *read* instead. pos mapping unchanged -> bitwise-same.
__global__ __launch_bounds__(256) void k_build(const int* __restrict__ adj,
    const int* __restrict__ rank, const int* __restrict__ offs,
    const float* __restrict__ as1, const float* __restrict__ ad1,
    uint4* __restrict__ wtab, int* __restrict__ perm, int E_, int n) {
  const int e = blockIdx.x * 256 + threadIdx.x;
  const int ET = E_ + n;
  if (e >= ET) return;
  int s, d;
  if (e < E_) { s = adj[e]; d = adj[E_ + e]; } else { s = d = e - E_; }
  perm[offs[d] + rank[e]] = e;          // the ONLY random write (4B, 3.4MB span)
  const float4 qs = *(const float4*)(as1 + (size_t)s * 4);
  const float4 qd = *(const float4*)(ad1 + (size_t)d * 4);
  float ev, w0, w1, w2, w3;
  ev = qs.x + qd.x; ev = (ev >= 0.f) ? ev : NEG * ev; w0 = __expf(ev);
  ev = qs.y + qd.y; ev = (ev >= 0.f) ? ev : NEG * ev; w1 = __expf(ev);
  ev = qs.z + qd.z; ev = (ev >= 0.f) ? ev : NEG * ev; w2 = __expf(ev);
  ev = qs.w + qd.w; ev = (ev >= 0.f) ? ev : NEG * ev; w3 = __expf(ev);
  uint4 rec;
  rec.x = (unsigned)s;
  rec.y = (unsigned)f2b(w0) | ((unsigned)f2b(w1) << 16);
  rec.z = (unsigned)f2b(w2) | ((unsigned)f2b(w3) << 16);
  rec.w = (unsigned)d;
  wtab[e] = rec;                        // coalesced 16B
}

// ------- fused GAT layer 1 (fp8 gather, quarter-wave per edge, perm indirection) -------
__global__ __launch_bounds__(256) void k_agg1(const unsigned char* __restrict__ h1f8,
    const int* __restrict__ offs, const int* __restrict__ perm,
    const uint4* __restrict__ wtab, const float* __restrict__ b1,
    unsigned short* __restrict__ relu1b, int n) {
  int node = blockIdx.x * 4 + (threadIdx.x >> 6);
  int lane = threadIdx.x & 63;
  if (node >= n) return;
  const int sub = lane >> 4;       // edge slot within group of 4
  const int p = lane & 15;         // feature 16-tuple
  const int h = p >> 2;            // head
  const bool hHi = (h & 2) != 0, hOdd = (h & 1) != 0;
  const int j0 = offs[node], j1 = offs[node + 1];
  float a[16];
#pragma unroll
  for (int i = 0; i < 16; ++i) a[i] = 0.f;
  float den = 0.f;
  int j = j0;
  for (; j + 8 <= j1; j += 8) {
    const int eA = perm[j + sub];
    const int eB = perm[j + 4 + sub];
    const uint4 rA = wtab[eA];
    const uint4 rB = wtab[eB];
    const uint4 uA = ((const uint4*)(h1f8 + (size_t)rA.x * F1))[p];
    const uint4 uB = ((const uint4*)(h1f8 + (size_t)rB.x * F1))[p];
    unsigned wbits; float w;
    v2f q;
    wbits = hHi ? rA.z : rA.y; w = hOdd ? b2fh(wbits) : b2fl(wbits);
    den += w;
    q = __builtin_amdgcn_cvt_pk_f32_fp8(uA.x, false); a[0] += w * q.x; a[1] += w * q.y;
    q = __builtin_amdgcn_cvt_pk_f32_fp8(uA.x, true);  a[2] += w * q.x; a[3] += w * q.y;
    q = __builtin_amdgcn_cvt_pk_f32_fp8(uA.y, false); a[4] += w * q.x; a[5] += w * q.y;
    q = __builtin_amdgcn_cvt_pk_f32_fp8(uA.y, true);  a[6] += w * q.x; a[7] += w * q.y;
    q = __builtin_amdgcn_cvt_pk_f32_fp8(uA.z, false); a[8] += w * q.x; a[9] += w * q.y;
    q = __builtin_amdgcn_cvt_pk_f32_fp8(uA.z, true);  a[10] += w * q.x; a[11] += w * q.y;
    q = __builtin_amdgcn_cvt_pk_f32_fp8(uA.w, false); a[12] += w * q.x; a[13] += w * q.y;
    q = __builtin_amdgcn_cvt_pk_f32_fp8(uA.w, true);  a[14] += w * q.x; a[15] += w * q.y;
    wbits = hHi ? rB.z : rB.y; w = hOdd ? b2fh(wbits) : b2fl(wbits);
    den += w;
    q = __builtin_amdgcn_cvt_pk_f32_fp8(uB.x, false); a[0] += w * q.x; a[1] += w * q.y;
    q = __builtin_amdgcn_cvt_pk_f32_fp8(uB.x, true);  a[2] += w * q.x; a[3] += w * q.y;
    q = __builtin_amdgcn_cvt_pk_f32_fp8(uB.y, false); a[4] += w * q.x; a[5] += w * q.y;
    q = __builtin_amdgcn_cvt_pk_f32_fp8(uB.y, true);  a[6] += w * q.x; a[7] += w * q.y;
    q = __builtin_amdgcn_cvt_pk_f32_fp8(uB.z, false); a[8] += w * q.x; a[9] += w * q.y;
    q = __builtin_amdgcn_cvt_pk_f32_fp8(uB.z, true);  a[10] += w * q.x; a[11] += w * q.y;
    q = __builtin_amdgcn_cvt_pk_f32_fp8(uB.w, false); a[12] += w * q.x; a[13] += w * q.y;
    q = __builtin_amdgcn_cvt_pk_f32_fp8(uB.w, true);  a[14] += w * q.x; a[15] += w * q.y;
  }
  for (; j < j1; j += 4) {
    const int idx = j + sub;
    const bool valid = idx < j1;
    const int ee = perm[valid ? idx : (j1 - 1)];
    const uint4 r = wtab[ee];
    const uint4 u = ((const uint4*)(h1f8 + (size_t)r.x * F1))[p];
    unsigned wbits = hHi ? r.z : r.y;
    float w = hOdd ? b2fh(wbits) : b2fl(wbits);
    if (!valid) w = 0.f;
    den += w;
    v2f q;
    q = __builtin_amdgcn_cvt_pk_f32_fp8(u.x, false); a[0] += w * q.x; a[1] += w * q.y;
    q = __builtin_amdgcn_cvt_pk_f32_fp8(u.x, true);  a[2] += w * q.x; a[3] += w * q.y;
    q = __builtin_amdgcn_cvt_pk_f32_fp8(u.y, false); a[4] += w * q.x; a[5] += w * q.y;
    q = __builtin_amdgcn_cvt_pk_f32_fp8(u.y, true);  a[6] += w * q.x; a[7] += w * q.y;
    q = __builtin_amdgcn_cvt_pk_f32_fp8(u.z, false); a[8] += w * q.x; a[9] += w * q.y;
    q = __builtin_amdgcn_cvt_pk_f32_fp8(u.z, true);  a[10] += w * q.x; a[11] += w * q.y;
    q = __builtin_amdgcn_cvt_pk_f32_fp8(u.w, false); a[12] += w * q.x; a[13] += w * q.y;
    q = __builtin_amdgcn_cvt_pk_f32_fp8(u.w, true);  a[14] += w * q.x; a[15] += w * q.y;
  }
  den += __shfl_xor(den, 16, 64); den += __shfl_xor(den, 32, 64);
#pragma unroll
  for (int i = 0; i < 16; ++i) {
    a[i] += __shfl_xor(a[i], 16, 64);
    a[i] += __shfl_xor(a[i], 32, 64);
  }
  if (sub == 0) {
    const float inv = 1.0f / den;
    ushort4 r0, r1, r2, r3;
    const float4 bb0 = ((const float4*)b1)[4 * p + 0];
    const float4 bb1 = ((const float4*)b1)[4 * p + 1];
    const float4 bb2 = ((const float4*)b1)[4 * p + 2];
    const float4 bb3 = ((const float4*)b1)[4 * p + 3];
    r0.x = f2b(fmaxf(a[0] * inv + bb0.x, 0.f));
    r0.y = f2b(fmaxf(a[1] * inv + bb0.y, 0.f));
    r0.z = f2b(fmaxf(a[2] * inv + bb0.z, 0.f));
    r0.w = f2b(fmaxf(a[3] * inv + bb0.w, 0.f));
    r1.x = f2b(fmaxf(a[4] * inv + bb1.x, 0.f));
    r1.y = f2b(fmaxf(a[5] * inv + bb1.y, 0.f));
    r1.z = f2b(fmaxf(a[6] * inv + bb1.z, 0.f));
    r1.w = f2b(fmaxf(a[7] * inv + bb1.w, 0.f));
    r2.x = f2b(fmaxf(a[8] * inv + bb2.x, 0.f));
    r2.y = f2b(fmaxf(a[9] * inv + bb2.y, 0.f));
    r2.z = f2b(fmaxf(a[10] * inv + bb2.z, 0.f));
    r2.w = f2b(fmaxf(a[11] * inv + bb2.w, 0.f));
    r3.x = f2b(fmaxf(a[12] * inv + bb3.x, 0.f));
    r3.y = f2b(fmaxf(a[13] * inv + bb3.y, 0.f));
    r3.z = f2b(fmaxf(a[14] * inv + bb3.z, 0.f));
    r3.w = f2b(fmaxf(a[15] * inv + bb3.w, 0.f));
    size_t base = (size_t)node * F1 + 16 * p;
    *(ushort4*)&relu1b[base + 0]  = r0;
    *(ushort4*)&relu1b[base + 4]  = r1;
    *(ushort4*)&relu1b[base + 8]  = r2;
    *(ushort4*)&relu1b[base + 12] = r3;
  }
}

// ---- GEMM2 via MFMA: h2[N,32] = relu1b(bf16) @ W2t(bf16); fused alpha2 dots ----
__global__ __launch_bounds__(256) void k_gemm2(const unsigned short* __restrict__ relu1b,
    const unsigned short* __restrict__ W2t, const float* __restrict__ a2s_w,
    const float* __restrict__ a2d_w, unsigned short* __restrict__ h2b,
    float* __restrict__ as2, float* __restrict__ ad2, int n) {
  const int tid = threadIdx.x;
  const int wv = tid >> 6, lane = tid & 63;
  const int l15 = lane & 15, quad = lane >> 4;
  const int row0 = blockIdx.x * 64 + wv * 16;
  v4f acc0 = {0.f, 0.f, 0.f, 0.f}, acc1 = acc0;
  const int arow = row0 + l15;
  const bool aok = arow < n;
#pragma unroll
  for (int kt = 0; kt < 8; ++kt) {
    const int ko = kt * 32 + quad * 8;
    short8 af = {0, 0, 0, 0, 0, 0, 0, 0};
    if (aok) af = *(const short8*)&relu1b[(size_t)arow * F1 + ko];
    short8 b0 = *(const short8*)&W2t[(size_t)l15 * F1 + ko];
    short8 b1 = *(const short8*)&W2t[(size_t)(16 + l15) * F1 + ko];
    acc0 = __builtin_amdgcn_mfma_f32_16x16x32_bf16(af, b0, acc0, 0, 0, 0);
    acc1 = __builtin_amdgcn_mfma_f32_16x16x32_bf16(af, b1, acc1, 0, 0, 0);
  }
  const float s0 = a2s_w[l15], s1 = a2s_w[16 + l15];
  const float d0 = a2d_w[l15], d1 = a2d_w[16 + l15];
#pragma unroll
  for (int r = 0; r < 4; ++r) {
    const int row = row0 + quad * 4 + r;
    const bool ok = row < n;
    if (ok) {
      h2b[(size_t)row * OUT_DIM + l15]      = f2b(acc0[r]);
      h2b[(size_t)row * OUT_DIM + 16 + l15] = f2b(acc1[r]);
    }
    float ss = acc0[r] * s0 + acc1[r] * s1;
    float sd = acc0[r] * d0 + acc1[r] * d1;
#pragma unroll
    for (int m = 1; m <= 8; m <<= 1) {
      ss += __shfl_xor(ss, m, 64);
      sd += __shfl_xor(sd, m, 64);
    }
    if (ok && l15 == 0) { as2[row] = ss; ad2[row] = sd; }
  }
}

// ---- w2 precompute: packed {src, w_bits} per edge (edge order, coalesced) ----
__global__ __launch_bounds__(256) void k_w2(const uint4* __restrict__ wtab,
    const float* __restrict__ as2, const float* __restrict__ ad2,
    uint2* __restrict__ sw2, int tot) {
  int e = blockIdx.x * 256 + threadIdx.x;
  if (e >= tot) return;
  uint4 r = wtab[e];
  float ev = as2[r.x] + ad2[r.w];
  ev = (ev >= 0.f) ? ev : NEG * ev;
  float w = __expf(ev);
  union { float f; unsigned i; } c; c.f = w;
  sw2[e] = make_uint2(r.x, c.i);
}

// -------- fused GAT layer 2 (bf16 gather, quarter-wave, perm indirection) --------
__global__ __launch_bounds__(256) void k_agg2(const unsigned short* __restrict__ h2b,
    const uint2* __restrict__ sw2, const int* __restrict__ offs,
    const int* __restrict__ perm, const float* __restrict__ b2,
    const float* __restrict__ linW, float* __restrict__ score, int n) {
  int node = blockIdx.x * 4 + (threadIdx.x >> 6);
  int lane = threadIdx.x & 63;
  if (node >= n) return;
  const int sub = lane >> 4;
  const int p = lane & 15;
  const int j0 = offs[node], j1 = offs[node + 1];
  float acc0 = 0.f, acc1 = 0.f, den = 0.f;
  union { unsigned i; float f; } cv;
  int jj = j0;
  for (; jj + 8 <= j1; jj += 8) {
    const int eA = perm[jj + sub];
    const int eB = perm[jj + 4 + sub];
    const uint2 rA = sw2[eA];
    const uint2 rB = sw2[eB];
    cv.i = rA.y; const float wA = cv.f;
    cv.i = rB.y; const float wB = cv.f;
    const unsigned uA = ((const unsigned*)(h2b + (size_t)rA.x * OUT_DIM))[p];
    const unsigned uB = ((const unsigned*)(h2b + (size_t)rB.x * OUT_DIM))[p];
    den += wA; acc0 += wA * b2fl(uA); acc1 += wA * b2fh(uA);
    den += wB; acc0 += wB * b2fl(uB); acc1 += wB * b2fh(uB);
  }
  for (; jj < j1; jj += 4) {
    const int idx = jj + sub;
    const bool valid = idx < j1;
    const int ee = perm[valid ? idx : (j1 - 1)];
    const uint2 r = sw2[ee];
    cv.i = r.y; float w = valid ? cv.f : 0.f;
    const unsigned u = ((const unsigned*)(h2b + (size_t)r.x * OUT_DIM))[p];
    den += w; acc0 += w * b2fl(u); acc1 += w * b2fh(u);
  }
  den  += __shfl_xor(den, 16, 64);  den  += __shfl_xor(den, 32, 64);
  acc0 += __shfl_xor(acc0, 16, 64); acc0 += __shfl_xor(acc0, 32, 64);
  acc1 += __shfl_xor(acc1, 16, 64); acc1 += __shfl_xor(acc1, 32, 64);
  const float inv = 1.0f / den;
  float o0 = acc0 * inv + b2[2 * p];
  float o1 = acc1 * inv + b2[2 * p + 1];
  float m = fmaxf(o0, o1);
#pragma unroll
  for (int mm = 1; mm <= 8; mm <<= 1) m = fmaxf(m, __shfl_xor(m, mm, 64));
  float ssum = __expf(o0 - m) + __expf(o1 - m);
#pragma unroll
  for (int mm = 1; mm <= 8; mm <<= 1) ssum += __shfl_xor(ssum, mm, 64);
  const float lse = m + __logf(ssum);
  float sc = (o0 - lse) * linW[2 * p] + (o1 - lse) * linW[2 * p + 1];
#pragma unroll
  for (int mm = 1; mm <= 8; mm <<= 1) sc += __shfl_xor(sc, mm, 64);
  if (lane == 0) score[node] = sc;
}

// -------- pooling: LDS per-graph partials, few global atomics per block --------
__global__ __launch_bounds__(256) void k_pool(const float* __restrict__ score,
    const int* __restrict__ batch, float* __restrict__ gsum,
    float* __restrict__ gcnt, int n) {
  __shared__ float ps[64];
  __shared__ float pc[64];
  const int tid = threadIdx.x;
  if (tid < 64) { ps[tid] = 0.f; pc[tid] = 0.f; }
  __syncthreads();
  int i = blockIdx.x * 256 + tid;
  if (i < n) {
    int g = batch[i];
    atomicAdd(&ps[g], score[i]);
    atomicAdd(&pc[g], 1.0f);
  }
  __syncthreads();
  if (tid < 64 && pc[tid] != 0.f) {
    atomicAdd(&gsum[tid], ps[tid]);
    atomicAdd(&gcnt[tid], pc[tid]);
  }
}

__global__ void k_final(const float* __restrict__ gsum, const float* __restrict__ gcnt,
                        const float* __restrict__ linb, float* __restrict__ out, int g_) {
  int g = threadIdx.x;
  if (g < g_) out[g] = gsum[g] / fmaxf(gcnt[g], 1.0f) + linb[0];
}

extern "C" void kernel_launch(void* const* d_in, const int* in_sizes, int n_in,
                              void* d_out, int out_size, void* d_ws, size_t ws_size,
                              hipStream_t stream) {
  const float* x    = (const float*)d_in[0];
  const int*   adj  = (const int*)d_in[1];
  const int*   batch= (const int*)d_in[2];
  const float* W1   = (const float*)d_in[3];
  const float* a1s  = (const float*)d_in[4];
  const float* a1d  = (const float*)d_in[5];
  const float* b1   = (const float*)d_in[6];
  const float* W2   = (const float*)d_in[7];
  const float* a2s  = (const float*)d_in[8];
  const float* a2d  = (const float*)d_in[9];
  const float* b2   = (const float*)d_in[10];
  const float* linW = (const float*)d_in[11];
  const float* linb = (const float*)d_in[12];

  const int N = in_sizes[0] / IN_DIM;
  const int E = in_sizes[1] / 2;
  const int ET = E + N;
  const int G = out_size;   // 64
  const int NB = (N + 1023) / 1024;   // must be <= 64 for merged scan (N=50000 -> 49)

  char* wsb = (char*)d_ws;
  size_t off = 0;
  auto take = [&](size_t bytes) -> char* {
    char* p = wsb + off;
    off += (bytes + 255) & ~(size_t)255;
    return p;
  };
  unsigned char* h1f8  = (unsigned char*)take((size_t)N * F1);
  unsigned short* relu1b= (unsigned short*)take((size_t)N * F1 * 2);
  float* as1    = (float*)take((size_t)N * 4 * 4);
  float* ad1    = (float*)take((size_t)N * 4 * 4);
  unsigned short* h2b = (unsigned short*)take((size_t)N * OUT_DIM * 2);
  float* as2v   = (float*)take((size_t)N * 4);
  float* ad2v   = (float*)take((size_t)N * 4);
  float* score  = (float*)take((size_t)N * 4);
  int*   cnt    = (int*)take((size_t)N * 4);
  int*   offs   = (int*)take((size_t)(N + 1) * 4);
  int*   rank   = (int*)take((size_t)ET * 4);
  uint4* wtab   = (uint4*)take((size_t)ET * 16);
  int*   perm   = (int*)take((size_t)ET * 4);
  uint2* sw2    = (uint2*)take((size_t)ET * 8);
  int*   bsum   = (int*)take((size_t)(NB + 1) * 4);
  float* gsum   = (float*)take((size_t)G * 4);
  float* gcnt   = (float*)take((size_t)G * 4);
  unsigned short* W1t = (unsigned short*)take((size_t)IN_DIM * F1 * 2);
  unsigned short* W2t = (unsigned short*)take((size_t)F1 * OUT_DIM * 2);
  (void)ws_size; (void)n_in;

  hipMemsetAsync(cnt, 0, (size_t)N * 4, stream);

  dim3 b256(256);
  k_prep_hist<<<dim3(160 + (ET + 255) / 256), b256, 0, stream>>>(
      W1, W1t, W2, W2t, adj, cnt, rank, E, N);
  k_gemm1<<<dim3((N + 63) / 64), b256, 0, stream>>>(x, W1t, a1s, a1d, h1f8, as1, ad1, N);
  k_scan_local<<<dim3(NB), b256, 0, stream>>>(cnt, offs, bsum, gsum, gcnt, N);
  k_scan_add<<<dim3((N + 255) / 256), b256, 0, stream>>>(offs, bsum, N, NB);
  k_build<<<dim3((ET + 255) / 256), b256, 0, stream>>>(adj, rank, offs, as1, ad1, wtab, perm, E, N);
  k_agg1<<<dim3((N + 3) / 4), b256, 0, stream>>>(h1f8, offs, perm, wtab, b1, relu1b, N);
  k_gemm2<<<dim3((N + 63) / 64), b256, 0, stream>>>(relu1b, W2t, a2s, a2d, h2b, as2v, ad2v, N);
  k_w2<<<dim3((ET + 255) / 256), b256, 0, stream>>>(wtab, as2v, ad2v, sw2, ET);
  k_agg2<<<dim3((N + 3) / 4), b256, 0, stream>>>(h2b, sw2, offs, perm, b2, linW, score, N);
  k_pool<<<dim3((N + 255) / 256), b256, 0, stream>>>(score, batch, gsum, gcnt, N);
  k_final<<<1, 64, 0, stream>>>(gsum, gcnt, linb, (float*)d_out, G);
}